// Round 3
// baseline (159.259 us; speedup 1.0000x reference)
//
#include <hip/hip_runtime.h>
#include <hip/hip_bf16.h>

#define NROWS 131072
#define KIN   784
#define KINP  800   // K padded for layer-1 weights (zeros beyond 784)
#define H1N   128
#define H2N   64
#define OUTN  10

typedef short s16x8 __attribute__((ext_vector_type(8)));
typedef float f32x4 __attribute__((ext_vector_type(4)));

typedef __hip_bfloat16 bf16;

static __device__ __forceinline__ short b2s(float f) {
    bf16 h = __float2bfloat16(f);
    return *reinterpret_cast<short*>(&h);
}

// load 8 contiguous f32 and convert to a bf16x8 MFMA fragment
static __device__ __forceinline__ s16x8 load_cvt8(const float* p) {
    f32x4 a = *(const f32x4*)p;
    f32x4 b = *(const f32x4*)(p + 4);
    s16x8 r;
    r[0] = b2s(a[0]); r[1] = b2s(a[1]); r[2] = b2s(a[2]); r[3] = b2s(a[3]);
    r[4] = b2s(b[0]); r[5] = b2s(b[1]); r[6] = b2s(b[2]); r[7] = b2s(b[3]);
    return r;
}

// ---------------- dequant: int4(int32) * f32 scale -> bf16 weights in ws ----
__global__ __launch_bounds__(256) void dequant_kernel(
    const int* __restrict__ w1q, const float* __restrict__ s1,
    const int* __restrict__ w2q, const float* __restrict__ s2,
    const int* __restrict__ w3q, const float* __restrict__ s3,
    bf16* __restrict__ w1d, bf16* __restrict__ w2d, bf16* __restrict__ w3d)
{
    const int total = H1N * KINP + H2N * H1N + 16 * H2N;
    for (int i = blockIdx.x * blockDim.x + threadIdx.x; i < total;
         i += gridDim.x * blockDim.x) {
        if (i < H1N * KINP) {
            int r = i / KINP, c = i - r * KINP;
            float v = 0.0f;
            if (c < KIN) v = (float)w1q[r * KIN + c] * s1[r];
            w1d[i] = __float2bfloat16(v);
        } else if (i < H1N * KINP + H2N * H1N) {
            int j = i - H1N * KINP;
            int r = j / H1N, c = j - r * H1N;
            w2d[j] = __float2bfloat16((float)w2q[r * H1N + c] * s2[r]);
        } else {
            int j = i - H1N * KINP - H2N * H1N;
            int r = j / H2N, c = j - r * H2N;
            float v = 0.0f;
            if (r < OUTN) v = (float)w3q[r * H2N + c] * s3[r];
            w3d[j] = __float2bfloat16(v);
        }
    }
}

// ---------------- fused MLP ------------------------------------------------
// block = 256 threads (4 waves), BM = 128 rows. Wave w owns rows w*32..w*32+31.
// Layer1: MFMA 16x16x32 bf16; A-frags loaded as f32 from global x and
// converted in-register to bf16; B-frags from L2-resident dequantized W1.
// fp32 accum; bias+relu -> h1 (LDS). Layers 2/3 from LDS.
__global__ __launch_bounds__(256) void mlp_kernel(
    const float* __restrict__ x,
    const bf16*  __restrict__ w1d,
    const bf16*  __restrict__ w2d,
    const bf16*  __restrict__ w3d,
    const float* __restrict__ b1,
    const float* __restrict__ b2,
    const float* __restrict__ b3,
    float* __restrict__ out)
{
    __shared__ __align__(16) short h1[128][136];  // bf16 bits; stride 272B
    __shared__ __align__(16) short h2[128][72];   // bf16 bits; stride 144B

    const int tid  = threadIdx.x;
    const int lane = tid & 63;
    const int wv   = tid >> 6;      // wave 0..3
    const int r16  = lane & 15;     // A-row / B-col / D-col within 16-tile
    const int kg   = lane >> 4;     // k-group 0..3 (8 contiguous k each)

    const long long row0 = (long long)blockIdx.x * 128 + wv * 32;
    const float* xa = x + (row0 + r16) * (long long)KIN;

    // ---- layer 1: [128 x 784] @ [784 x 128] ----
    f32x4 acc1[2][8];
#pragma unroll
    for (int i = 0; i < 2; ++i)
#pragma unroll
        for (int j = 0; j < 8; ++j) acc1[i][j] = (f32x4){0.f, 0.f, 0.f, 0.f};

#pragma unroll 4
    for (int k0 = 0; k0 < 768; k0 += 32) {
        const int kk = k0 + kg * 8;
        s16x8 a0 = load_cvt8(xa + kk);
        s16x8 a1 = load_cvt8(xa + 16 * KIN + kk);
#pragma unroll
        for (int nj = 0; nj < 8; ++nj) {
            s16x8 b = *(const s16x8*)(w1d + (nj * 16 + r16) * KINP + kk);
            acc1[0][nj] = __builtin_amdgcn_mfma_f32_16x16x32_bf16(a0, b, acc1[0][nj], 0, 0, 0);
            acc1[1][nj] = __builtin_amdgcn_mfma_f32_16x16x32_bf16(a1, b, acc1[1][nj], 0, 0, 0);
        }
    }
    {   // K tail: k0 = 768, only k-groups 0,1 are in-range (784 = 768+16)
        const int kk = 768 + kg * 8;
        s16x8 a0 = {}, a1 = {};
        if (kg < 2) {
            a0 = load_cvt8(xa + kk);
            a1 = load_cvt8(xa + 16 * KIN + kk);
        }
#pragma unroll
        for (int nj = 0; nj < 8; ++nj) {
            s16x8 b = *(const s16x8*)(w1d + (nj * 16 + r16) * KINP + kk); // zero-padded
            acc1[0][nj] = __builtin_amdgcn_mfma_f32_16x16x32_bf16(a0, b, acc1[0][nj], 0, 0, 0);
            acc1[1][nj] = __builtin_amdgcn_mfma_f32_16x16x32_bf16(a1, b, acc1[1][nj], 0, 0, 0);
        }
    }
    // bias + relu -> h1 (D layout: col = lane&15, row = (lane>>4)*4 + r)
#pragma unroll
    for (int mi = 0; mi < 2; ++mi)
#pragma unroll
        for (int nj = 0; nj < 8; ++nj) {
            const int col = nj * 16 + r16;
            const float bb = b1[col];
#pragma unroll
            for (int r = 0; r < 4; ++r) {
                const int row = wv * 32 + mi * 16 + kg * 4 + r;
                h1[row][col] = b2s(fmaxf(acc1[mi][nj][r] + bb, 0.0f));
            }
        }
    __syncthreads();

    // ---- layer 2: [128 x 128] @ [128 x 64] ----
    f32x4 acc2[2][4];
#pragma unroll
    for (int i = 0; i < 2; ++i)
#pragma unroll
        for (int j = 0; j < 4; ++j) acc2[i][j] = (f32x4){0.f, 0.f, 0.f, 0.f};

#pragma unroll
    for (int k0 = 0; k0 < 128; k0 += 32) {
        const int kk = k0 + kg * 8;
        s16x8 a0 = *(const s16x8*)&h1[wv * 32 + r16][kk];
        s16x8 a1 = *(const s16x8*)&h1[wv * 32 + 16 + r16][kk];
#pragma unroll
        for (int nj = 0; nj < 4; ++nj) {
            s16x8 b = *(const s16x8*)(w2d + (nj * 16 + r16) * H1N + kk);
            acc2[0][nj] = __builtin_amdgcn_mfma_f32_16x16x32_bf16(a0, b, acc2[0][nj], 0, 0, 0);
            acc2[1][nj] = __builtin_amdgcn_mfma_f32_16x16x32_bf16(a1, b, acc2[1][nj], 0, 0, 0);
        }
    }
#pragma unroll
    for (int mi = 0; mi < 2; ++mi)
#pragma unroll
        for (int nj = 0; nj < 4; ++nj) {
            const int col = nj * 16 + r16;
            const float bb = b2[col];
#pragma unroll
            for (int r = 0; r < 4; ++r) {
                const int row = wv * 32 + mi * 16 + kg * 4 + r;
                h2[row][col] = b2s(fmaxf(acc2[mi][nj][r] + bb, 0.0f));
            }
        }
    __syncthreads();

    // ---- layer 3: [128 x 64] @ [64 x 16] (cols 10..15 are zero rows of W3) ----
    f32x4 acc3[2];
#pragma unroll
    for (int i = 0; i < 2; ++i) acc3[i] = (f32x4){0.f, 0.f, 0.f, 0.f};

#pragma unroll
    for (int k0 = 0; k0 < 64; k0 += 32) {
        const int kk = k0 + kg * 8;
        s16x8 a0 = *(const s16x8*)&h2[wv * 32 + r16][kk];
        s16x8 a1 = *(const s16x8*)&h2[wv * 32 + 16 + r16][kk];
        s16x8 b  = *(const s16x8*)(w3d + r16 * H2N + kk);
        acc3[0] = __builtin_amdgcn_mfma_f32_16x16x32_bf16(a0, b, acc3[0], 0, 0, 0);
        acc3[1] = __builtin_amdgcn_mfma_f32_16x16x32_bf16(a1, b, acc3[1], 0, 0, 0);
    }

    // stage f32 outputs in LDS (reuse h1; all h1 reads done before the h2
    // __syncthreads above), then write coalesced.
    float* ob = (float*)&h1[0][0];   // 128*10 f32 = 5120 B
    const float bb3 = (r16 < OUTN) ? b3[r16] : 0.0f;
#pragma unroll
    for (int mi = 0; mi < 2; ++mi)
#pragma unroll
        for (int r = 0; r < 4; ++r) {
            const int row = wv * 32 + mi * 16 + kg * 4 + r;
            if (r16 < OUTN) ob[row * OUTN + r16] = acc3[mi][r] + bb3;
        }
    __syncthreads();

    const long long obase = (long long)blockIdx.x * 128 * OUTN;
    for (int i = tid; i < 128 * OUTN; i += 256) out[obase + i] = ob[i];
}

extern "C" void kernel_launch(void* const* d_in, const int* in_sizes, int n_in,
                              void* d_out, int out_size, void* d_ws, size_t ws_size,
                              hipStream_t stream) {
    const float* x   = (const float*)d_in[0];
    const int*   w1q = (const int*)d_in[1];
    const float* s1  = (const float*)d_in[2];
    const float* b1  = (const float*)d_in[3];
    const int*   w2q = (const int*)d_in[4];
    const float* s2  = (const float*)d_in[5];
    const float* b2  = (const float*)d_in[6];
    const int*   w3q = (const int*)d_in[7];
    const float* s3  = (const float*)d_in[8];
    const float* b3  = (const float*)d_in[9];
    float* out = (float*)d_out;

    bf16* w1d = (bf16*)d_ws;            // [128][800]
    bf16* w2d = w1d + H1N * KINP;       // [64][128]
    bf16* w3d = w2d + H2N * H1N;        // [16][64]

    dequant_kernel<<<112, 256, 0, stream>>>(w1q, s1, w2q, s2, w3q, s3, w1d, w2d, w3d);
    mlp_kernel<<<NROWS / 128, 256, 0, stream>>>(x, w1d, w2d, w3d, b1, b2, b3, out);
}

// Round 4
// 123.445 us; speedup vs baseline: 1.2901x; 1.2901x over previous
//
#include <hip/hip_runtime.h>
#include <hip/hip_bf16.h>

#define NROWS 131072
#define KIN   784
#define KINP  800   // K padded for layer-1 weights (zeros beyond 784)
#define H1N   128
#define H2N   64
#define OUTN  10

// chunked weight layouts: w1c[kb][col][8] with kb = k/8  (k in [0,800))
#define W1C_ELEMS (100 * 128 * 8)   // 102400
#define W2C_ELEMS (16 * 64 * 8)     // 8192
#define W3_ELEMS  (16 * 64)         // 1024

typedef short s16x8 __attribute__((ext_vector_type(8)));
typedef float f32x4 __attribute__((ext_vector_type(4)));

typedef __hip_bfloat16 bf16;

static __device__ __forceinline__ short b2s(float f) {
    bf16 h = __float2bfloat16(f);
    return *reinterpret_cast<short*>(&h);
}

static __device__ __forceinline__ s16x8 cvt8(f32x4 a, f32x4 b) {
    s16x8 r;
    r[0] = b2s(a[0]); r[1] = b2s(a[1]); r[2] = b2s(a[2]); r[3] = b2s(a[3]);
    r[4] = b2s(b[0]); r[5] = b2s(b[1]); r[6] = b2s(b[2]); r[7] = b2s(b[3]);
    return r;
}

// ---------------- dequant: int4(int32) * f32 scale -> bf16 (chunked layouts) --
__global__ __launch_bounds__(256) void dequant_kernel(
    const int* __restrict__ w1q, const float* __restrict__ s1,
    const int* __restrict__ w2q, const float* __restrict__ s2,
    const int* __restrict__ w3q, const float* __restrict__ s3,
    bf16* __restrict__ w1c, bf16* __restrict__ w2c, bf16* __restrict__ w3d)
{
    const int total = W1C_ELEMS + W2C_ELEMS + W3_ELEMS;
    for (int i = blockIdx.x * blockDim.x + threadIdx.x; i < total;
         i += gridDim.x * blockDim.x) {
        if (i < W1C_ELEMS) {
            int kb = i >> 10, rem = i & 1023;
            int col = rem >> 3, j = rem & 7;
            int k = kb * 8 + j;
            float v = 0.0f;
            if (k < KIN) v = (float)w1q[col * KIN + k] * s1[col];
            w1c[i] = __float2bfloat16(v);
        } else if (i < W1C_ELEMS + W2C_ELEMS) {
            int t = i - W1C_ELEMS;
            int kb = t >> 9, rem = t & 511;
            int col = rem >> 3, j = rem & 7;
            int k = kb * 8 + j;
            w2c[t] = __float2bfloat16((float)w2q[col * H1N + k] * s2[col]);
        } else {
            int t = i - W1C_ELEMS - W2C_ELEMS;
            int r = t >> 6, c = t & 63;
            float v = 0.0f;
            if (r < OUTN) v = (float)w3q[r * H2N + c] * s3[r];
            w3d[t] = __float2bfloat16(v);
        }
    }
}

// ---------------- fused MLP ------------------------------------------------
// 256 threads (4 waves), BM=128 rows/block, wave w owns rows w*32..w*32+31.
// LDS = 33.8 KB -> 4 blocks/CU resident, grid 1024 = one balanced round.
// Layer1: A raw-f32 prefetched 1 iter ahead, cvt->bf16 in-reg, MFMA 16x16x32
// bf16 with k-chunked W1 (one base + imm offsets). fp32 accum throughout.
__global__ __launch_bounds__(256, 4) void mlp_kernel(
    const float* __restrict__ x,
    const bf16*  __restrict__ w1c,
    const bf16*  __restrict__ w2c,
    const bf16*  __restrict__ w3d,
    const float* __restrict__ b1,
    const float* __restrict__ b2,
    const float* __restrict__ b3,
    float* __restrict__ out)
{
    __shared__ __align__(16) short h1[128][132];   // 33,792 B; all phases overlay here

    const int tid  = threadIdx.x;
    const int lane = tid & 63;
    const int wv   = tid >> 6;      // wave 0..3
    const int r16  = lane & 15;
    const int kg   = lane >> 4;     // 0..3
    const int kgo  = kg * 8;

    const long long row0 = (long long)blockIdx.x * 128 + wv * 32;
    const float* xa0 = x + (row0 + r16) * (long long)KIN + kgo;
    const float* xa1 = xa0 + 16LL * KIN;

    // ---- layer 1: [128 x 784] @ [784 x 128] ----
    f32x4 acc1[2][8];
#pragma unroll
    for (int i = 0; i < 2; ++i)
#pragma unroll
        for (int j = 0; j < 8; ++j) acc1[i][j] = (f32x4){0.f, 0.f, 0.f, 0.f};

    // prologue: raw prefetch of iteration 0
    f32x4 p0l = *(const f32x4*)(xa0);
    f32x4 p0h = *(const f32x4*)(xa0 + 4);
    f32x4 p1l = *(const f32x4*)(xa1);
    f32x4 p1h = *(const f32x4*)(xa1 + 4);

    const bf16* bp = w1c + (size_t)kg * 1024 + (size_t)r16 * 8;

#pragma unroll 1
    for (int it = 0; it < 25; ++it) {
        s16x8 a0 = cvt8(p0l, p0h);
        s16x8 a1 = cvt8(p1l, p1h);

        const int nx = (it + 1) * 32;   // next k0
        if (it < 23) {
            p0l = *(const f32x4*)(xa0 + nx);
            p0h = *(const f32x4*)(xa0 + nx + 4);
            p1l = *(const f32x4*)(xa1 + nx);
            p1h = *(const f32x4*)(xa1 + nx + 4);
        } else if (it == 23) {          // next k0 = 768: only kg 0,1 in range
            if (kg < 2) {
                p0l = *(const f32x4*)(xa0 + nx);
                p0h = *(const f32x4*)(xa0 + nx + 4);
                p1l = *(const f32x4*)(xa1 + nx);
                p1h = *(const f32x4*)(xa1 + nx + 4);
            } else {
                p0l = (f32x4){0.f,0.f,0.f,0.f}; p0h = p0l;
                p1l = p0l;                       p1h = p0l;
            }
        }

#pragma unroll
        for (int nj = 0; nj < 8; ++nj) {
            s16x8 b = *(const s16x8*)(bp + nj * 128);   // imm offsets nj*256B
            acc1[0][nj] = __builtin_amdgcn_mfma_f32_16x16x32_bf16(a0, b, acc1[0][nj], 0, 0, 0);
            acc1[1][nj] = __builtin_amdgcn_mfma_f32_16x16x32_bf16(a1, b, acc1[1][nj], 0, 0, 0);
        }
        bp += 4096;   // 4 kb-chunks of 1024 elems
    }

    // bias + relu -> h1 (D layout: col = lane&15, row = (lane>>4)*4 + r)
#pragma unroll
    for (int mi = 0; mi < 2; ++mi)
#pragma unroll
        for (int nj = 0; nj < 8; ++nj) {
            const int col = nj * 16 + r16;
            const float bb = b1[col];
#pragma unroll
            for (int r = 0; r < 4; ++r) {
                const int row = wv * 32 + mi * 16 + kg * 4 + r;
                h1[row][col] = b2s(fmaxf(acc1[mi][nj][r] + bb, 0.0f));
            }
        }
    __syncthreads();

    // ---- layer 2: [128 x 128] @ [128 x 64] ----
    f32x4 acc2[2][4];
#pragma unroll
    for (int i = 0; i < 2; ++i)
#pragma unroll
        for (int j = 0; j < 4; ++j) acc2[i][j] = (f32x4){0.f, 0.f, 0.f, 0.f};

#pragma unroll
    for (int it = 0; it < 4; ++it) {
        const int kk = it * 32 + kgo;
        s16x8 a0 = *(const s16x8*)&h1[wv * 32 + r16][kk];
        s16x8 a1 = *(const s16x8*)&h1[wv * 32 + 16 + r16][kk];
        const bf16* bp2 = w2c + (size_t)(it * 4 + kg) * 512 + (size_t)r16 * 8;
#pragma unroll
        for (int nj = 0; nj < 4; ++nj) {
            s16x8 b = *(const s16x8*)(bp2 + nj * 128);
            acc2[0][nj] = __builtin_amdgcn_mfma_f32_16x16x32_bf16(a0, b, acc2[0][nj], 0, 0, 0);
            acc2[1][nj] = __builtin_amdgcn_mfma_f32_16x16x32_bf16(a1, b, acc2[1][nj], 0, 0, 0);
        }
    }
    __syncthreads();   // all h1 reads done -> safe to overlay

    // write h2 overlay into the same LDS
    short (*h2)[68] = (short(*)[68])&h1[0][0];   // 17,408 B
#pragma unroll
    for (int mi = 0; mi < 2; ++mi)
#pragma unroll
        for (int nj = 0; nj < 4; ++nj) {
            const int col = nj * 16 + r16;
            const float bb = b2[col];
#pragma unroll
            for (int r = 0; r < 4; ++r) {
                const int row = wv * 32 + mi * 16 + kg * 4 + r;
                h2[row][col] = b2s(fmaxf(acc2[mi][nj][r] + bb, 0.0f));
            }
        }
    __syncthreads();

    // ---- layer 3: [128 x 64] @ [64 x 16] (rows 10..15 of W3 are zero) ----
    f32x4 acc3[2];
#pragma unroll
    for (int i = 0; i < 2; ++i) acc3[i] = (f32x4){0.f, 0.f, 0.f, 0.f};

#pragma unroll
    for (int it = 0; it < 2; ++it) {
        const int kk = it * 32 + kgo;
        s16x8 a0 = *(const s16x8*)&h2[wv * 32 + r16][kk];
        s16x8 a1 = *(const s16x8*)&h2[wv * 32 + 16 + r16][kk];
        s16x8 b  = *(const s16x8*)(w3d + r16 * H2N + kk);
        acc3[0] = __builtin_amdgcn_mfma_f32_16x16x32_bf16(a0, b, acc3[0], 0, 0, 0);
        acc3[1] = __builtin_amdgcn_mfma_f32_16x16x32_bf16(a1, b, acc3[1], 0, 0, 0);
    }
    __syncthreads();   // all h2 reads done -> safe to overlay

    // stage f32 outputs, then write coalesced
    float* ob = (float*)&h1[0][0];   // 5,120 B
    const float bb3 = (r16 < OUTN) ? b3[r16] : 0.0f;
#pragma unroll
    for (int mi = 0; mi < 2; ++mi)
#pragma unroll
        for (int r = 0; r < 4; ++r) {
            const int row = wv * 32 + mi * 16 + kg * 4 + r;
            if (r16 < OUTN) ob[row * OUTN + r16] = acc3[mi][r] + bb3;
        }
    __syncthreads();

    const long long obase = (long long)blockIdx.x * 128 * OUTN;
    for (int i = tid; i < 128 * OUTN; i += 256) out[obase + i] = ob[i];
}

extern "C" void kernel_launch(void* const* d_in, const int* in_sizes, int n_in,
                              void* d_out, int out_size, void* d_ws, size_t ws_size,
                              hipStream_t stream) {
    const float* x   = (const float*)d_in[0];
    const int*   w1q = (const int*)d_in[1];
    const float* s1  = (const float*)d_in[2];
    const float* b1  = (const float*)d_in[3];
    const int*   w2q = (const int*)d_in[4];
    const float* s2  = (const float*)d_in[5];
    const float* b2  = (const float*)d_in[6];
    const int*   w3q = (const int*)d_in[7];
    const float* s3  = (const float*)d_in[8];
    const float* b3  = (const float*)d_in[9];
    float* out = (float*)d_out;

    bf16* w1c = (bf16*)d_ws;              // [100][128][8]
    bf16* w2c = w1c + W1C_ELEMS;          // [16][64][8]
    bf16* w3d = w2c + W2C_ELEMS;          // [16][64]

    dequant_kernel<<<128, 256, 0, stream>>>(w1q, s1, w2q, s2, w3q, s3, w1c, w2c, w3d);
    mlp_kernel<<<NROWS / 128, 256, 0, stream>>>(x, w1c, w2c, w3d, b1, b2, b3, out);
}